// Round 13
// baseline (178.162 us; speedup 1.0000x reference)
//
#include <hip/hip_runtime.h>

// CausalSelfAttention: B=4, T=2048, C=1024, H=16, hd=64
// fused prep, QKV GEMM (128^2, A-single/B-dbuf, counted vmcnt, conflict-free swizzle,
// per-block K-rotation to break inter-block convoy), 8-wave flash attention, proj GEMM

#define T_SEQ 2048
#define NB 4
#define NH 16
#define CDIM 1024
#define HD 64
#define BH (NB * NH)
#define QSCALE 0.1803368801111204f  // 0.125 * log2(e)

typedef float f32x4 __attribute__((ext_vector_type(4)));
typedef float f32x16 __attribute__((ext_vector_type(16)));
typedef __bf16 bf16x8 __attribute__((ext_vector_type(8)));
typedef unsigned short u16x8 __attribute__((ext_vector_type(8)));
typedef unsigned short u16x4 __attribute__((ext_vector_type(4)));

__device__ __forceinline__ unsigned short f2b(float f) {
    union { float f; unsigned u; } v; v.f = f;
    unsigned u = v.u;
    u += 0x7FFFu + ((u >> 16) & 1u);   // round-to-nearest-even
    return (unsigned short)(u >> 16);
}

__device__ __forceinline__ f32x4 fzero4() {
    f32x4 z; z[0] = 0.f; z[1] = 0.f; z[2] = 0.f; z[3] = 0.f; return z;
}

__device__ __forceinline__ f32x4 mfma16(bf16x8 a, bf16x8 b, f32x4 c) {
    return __builtin_amdgcn_mfma_f32_16x16x32_bf16(a, b, c, 0, 0, 0);
}

__device__ __forceinline__ f32x16 mfma32(bf16x8 a, bf16x8 b, f32x16 c) {
    return __builtin_amdgcn_mfma_f32_32x32x16_bf16(a, b, c, 0, 0, 0);
}

// async global->LDS, 16B/lane; LDS dest = wave-uniform base + lane*16 (HW rule)
__device__ __forceinline__ void gld16(const void* gp, void* lp) {
    __builtin_amdgcn_global_load_lds(
        (const __attribute__((address_space(1))) unsigned int*)gp,
        (__attribute__((address_space(3))) unsigned int*)lp, 16, 0, 0);
}

#define FENCE asm volatile("" ::: "memory")

// ---------------- fused prep: cast x, transpose w_attn, transpose w_proj ----------------
__device__ __forceinline__ void transpose_tile(
        const float* __restrict__ in, unsigned short* __restrict__ out,
        int R, int C, int bx, int by) {
    __shared__ unsigned short tile[32][33];
    int tx = threadIdx.x & 31, ty = threadIdx.x >> 5;
    int c0 = bx * 32, r0 = by * 32;
#pragma unroll
    for (int rr = ty; rr < 32; rr += 8)
        tile[rr][tx] = f2b(in[(size_t)(r0 + rr) * C + c0 + tx]);
    __syncthreads();
#pragma unroll
    for (int rr = ty; rr < 32; rr += 8)
        out[(size_t)(c0 + rr) * R + r0 + tx] = tile[tx][rr];
}

__global__ __launch_bounds__(256) void prep_kernel(
        const float* __restrict__ x, const float* __restrict__ wa,
        const float* __restrict__ wp, unsigned short* __restrict__ xb,
        unsigned short* __restrict__ wTa, unsigned short* __restrict__ wTp) {
    int b = blockIdx.x;
    if (b < 1024) {
        int n8 = (NB * T_SEQ * CDIM) / 8;
        for (int i = b * 256 + threadIdx.x; i < n8; i += 1024 * 256) {
            const float4* p = reinterpret_cast<const float4*>(x) + (size_t)i * 2;
            float4 a = p[0], c = p[1];
            u16x8 o;
            o[0] = f2b(a.x); o[1] = f2b(a.y); o[2] = f2b(a.z); o[3] = f2b(a.w);
            o[4] = f2b(c.x); o[5] = f2b(c.y); o[6] = f2b(c.z); o[7] = f2b(c.w);
            *(reinterpret_cast<u16x8*>(xb) + i) = o;
        }
    } else if (b < 1024 + 3072) {
        int t = b - 1024;   // w_attn [1024][3072]: 96 x 32 tiles
        transpose_tile(wa, wTa, 1024, 3072, t % 96, t / 96);
    } else {
        int t = b - 4096;   // w_proj [1024][1024]: 32 x 32 tiles
        transpose_tile(wp, wTp, 1024, 1024, t % 32, t / 32);
    }
}

// ---------------- QKV GEMM: 128^2, A-single + B-dbuf, K-rotated ----------------
// Each block processes K-tiles in order (it + phase) mod 32, phase spread so the
// ~6 co-resident blocks on a CU stall at different wall-clock times (anti-convoy).
__global__ __launch_bounds__(256) void gemm_qkv_kernel(
        const unsigned short* __restrict__ A, const unsigned short* __restrict__ Bt,
        const float* __restrict__ bias,
        unsigned short* __restrict__ q_out, unsigned short* __restrict__ k_out,
        unsigned short* __restrict__ v_out, int M, int N, int K) {
    __shared__ alignas(16) unsigned short As[128 * 32];     // 8KB single
    __shared__ alignas(16) unsigned short Bs[2][128 * 32];  // 16KB dbuf

    int tid = threadIdx.x;
    int wid = tid >> 6, lane = tid & 63;
    int g = lane >> 4, lc = lane & 15;
    int wr = (wid >> 1) * 64, wc = (wid & 1) * 64;
    int m0 = blockIdx.y * 128, n0 = blockIdx.x * 128;

    int nk = K >> 5;
    int bid = blockIdx.y * gridDim.x + blockIdx.x;
    int phase = (bid + 5 * (bid >> 8)) & (nk - 1);  // co-resident blocks (ids ~256 apart) get spread phases

    f32x4 acc[4][4];
#pragma unroll
    for (int m = 0; m < 4; ++m)
#pragma unroll
        for (int n = 0; n < 4; ++n) acc[m][n] = fzero4();

    int srow = tid >> 2;
    int scol = ((tid & 3) ^ ((srow >> 1) & 3)) * 8;  // inverse-swizzled source col
    const unsigned short* Ap = A + (size_t)(m0 + srow) * K + scol;
    const unsigned short* Bp = Bt + (size_t)(n0 + srow) * K + scol;
    int ldst = (wid * 16) * 32;
    int ldst2 = (64 + wid * 16) * 32;

#define STAGE_A(KT) {                                              \
        int ko_ = (KT) << 5;                                       \
        gld16(Ap + ko_, &As[ldst]);                                \
        gld16(Ap + (size_t)64 * K + ko_, &As[ldst2]); }
#define STAGE_B(BUF, KT) {                                                 \
        int ko_ = (KT) << 5;                                               \
        gld16(Bp + ko_, &Bs[BUF][ldst]);                                   \
        gld16(Bp + (size_t)64 * K + ko_, &Bs[BUF][ldst2]); }

    STAGE_B(0, phase)                   // B(p)
    STAGE_A(phase)                      // A(p)
    STAGE_B(1, (phase + 1) & (nk - 1))  // B(p+1)

    int swz8 = (g ^ ((lc >> 1) & 3)) * 8;  // read slot swizzle ((row>>1)&3 == (lc>>1)&3)

    for (int it = 0; it < nk; ++it) {
        if (it + 1 < nk) { asm volatile("s_waitcnt vmcnt(2)" ::: "memory"); }
        else             { asm volatile("s_waitcnt vmcnt(0)" ::: "memory"); }
        FENCE; __builtin_amdgcn_s_barrier(); FENCE;  // A(it), B(it) visible

        bf16x8 af[4], bfr[4];
        const unsigned short* Bb = Bs[it & 1];
#pragma unroll
        for (int m = 0; m < 4; ++m)
            af[m] = *(const bf16x8*)&As[(wr + m * 16 + lc) * 32 + swz8];
#pragma unroll
        for (int n = 0; n < 4; ++n)
            bfr[n] = *(const bf16x8*)&Bb[(wc + n * 16 + lc) * 32 + swz8];

        __builtin_amdgcn_s_setprio(1);
#pragma unroll
        for (int m = 0; m < 4; ++m)
#pragma unroll
            for (int n = 0; n < 4; ++n)
                acc[m][n] = mfma16(af[m], bfr[n], acc[m][n]);
        __builtin_amdgcn_s_setprio(0);

        asm volatile("s_waitcnt lgkmcnt(0)" ::: "memory");
        FENCE; __builtin_amdgcn_s_barrier(); FENCE;  // all reads consumed
        if (it + 1 < nk) STAGE_A((it + 1 + phase) & (nk - 1))
        if (it + 2 < nk) STAGE_B(it & 1, (it + 2 + phase) & (nk - 1))
    }
#undef STAGE_A
#undef STAGE_B

    // epilogue: scatter q (scaled), k row-major; v transposed per head
#pragma unroll
    for (int m = 0; m < 4; ++m) {
        int rowb = m0 + wr + m * 16 + g * 4;
#pragma unroll
        for (int n = 0; n < 4; ++n) {
            int col = n0 + wc + n * 16 + lc;
            float bv = bias[col];
            int which = col >> 10;
            int c = col & 1023;
            int h = c >> 6, d = c & 63;
            int bh_ = (rowb >> 11) * NH + h;
            int tl = rowb & 2047;
            if (which == 2) {
                u16x4 vq;
#pragma unroll
                for (int i = 0; i < 4; ++i) vq[i] = f2b(acc[m][n][i] + bv);
                *(u16x4*)&v_out[(size_t)bh_ * (HD * T_SEQ) + (size_t)d * T_SEQ + tl] = vq;
            } else {
                unsigned short* dst = which ? k_out : q_out;
                float sc = which ? 1.0f : QSCALE;
#pragma unroll
                for (int i = 0; i < 4; ++i)
                    dst[((size_t)bh_ * T_SEQ + tl + i) * HD + d] =
                        f2b((acc[m][n][i] + bv) * sc);
            }
        }
    }
}

// ---------------- proj GEMM: 128^2 2-phase dbuf + counted vmcnt, K-rotated ----------
__global__ __launch_bounds__(256) void gemm_proj_kernel(
        const unsigned short* __restrict__ A, const unsigned short* __restrict__ Bt,
        const float* __restrict__ bias, float* __restrict__ outF, int M, int N, int K) {
    __shared__ alignas(16) unsigned short As[2][128 * 32];
    __shared__ alignas(16) unsigned short Bs[2][128 * 32];

    int tid = threadIdx.x;
    int wid = tid >> 6, lane = tid & 63;
    int g = lane >> 4, lc = lane & 15;
    int wr = (wid >> 1) * 64, wc = (wid & 1) * 64;
    int m0 = blockIdx.y * 128, n0 = blockIdx.x * 128;

    int nk = K >> 5;
    int bid = blockIdx.y * gridDim.x + blockIdx.x;
    int phase = (bid + 5 * (bid >> 8)) & (nk - 1);

    f32x4 acc[4][4];
#pragma unroll
    for (int m = 0; m < 4; ++m)
#pragma unroll
        for (int n = 0; n < 4; ++n) acc[m][n] = fzero4();

    int srow = tid >> 2;
    int scol = ((tid & 3) ^ ((srow >> 1) & 3)) * 8;
    const unsigned short* Ap = A + (size_t)(m0 + srow) * K + scol;
    const unsigned short* Bp = Bt + (size_t)(n0 + srow) * K + scol;
    int ldst = (wid * 16) * 32;
    int ldst2 = (64 + wid * 16) * 32;

#define GSTAGE(BUF, KT) {                                          \
        int ko_ = (KT) << 5;                                       \
        gld16(Ap + ko_, &As[BUF][ldst]);                           \
        gld16(Ap + (size_t)64 * K + ko_, &As[BUF][ldst2]);         \
        gld16(Bp + ko_, &Bs[BUF][ldst]);                           \
        gld16(Bp + (size_t)64 * K + ko_, &Bs[BUF][ldst2]); }

    GSTAGE(0, phase)
    GSTAGE(1, (phase + 1) & (nk - 1))

    int swz8 = (g ^ ((lc >> 1) & 3)) * 8;

    for (int it = 0; it < nk; ++it) {
        int cur = it & 1;
        if (it + 1 < nk) { asm volatile("s_waitcnt vmcnt(4)" ::: "memory"); }
        else             { asm volatile("s_waitcnt vmcnt(0)" ::: "memory"); }
        FENCE; __builtin_amdgcn_s_barrier(); FENCE;

        bf16x8 af[4], bfr[4];
#pragma unroll
        for (int m = 0; m < 4; ++m)
            af[m] = *(const bf16x8*)&As[cur][(wr + m * 16 + lc) * 32 + swz8];
#pragma unroll
        for (int n = 0; n < 4; ++n)
            bfr[n] = *(const bf16x8*)&Bs[cur][(wc + n * 16 + lc) * 32 + swz8];

        __builtin_amdgcn_s_setprio(1);
#pragma unroll
        for (int m = 0; m < 4; ++m)
#pragma unroll
            for (int n = 0; n < 4; ++n)
                acc[m][n] = mfma16(af[m], bfr[n], acc[m][n]);
        __builtin_amdgcn_s_setprio(0);

        FENCE; __builtin_amdgcn_s_barrier(); FENCE;
        if (it + 2 < nk) { GSTAGE(cur, (it + 2 + phase) & (nk - 1)) }
    }
#undef GSTAGE

#pragma unroll
    for (int m = 0; m < 4; ++m) {
        int rowb = m0 + wr + m * 16 + g * 4;
#pragma unroll
        for (int n = 0; n < 4; ++n) {
            int col = n0 + wc + n * 16 + lc;
            float bv = bias[col];
#pragma unroll
            for (int i = 0; i < 4; ++i)
                outF[(size_t)(rowb + i) * N + col] = acc[m][n][i] + bv;
        }
    }
}

// ---------------- flash attention: 8 waves/block, 256 q-rows, swapped QK^T ----------------
__global__ __launch_bounds__(512, 4) void attn32_kernel(
        const unsigned short* __restrict__ Qb, const unsigned short* __restrict__ Kb,
        const unsigned short* __restrict__ Vt, unsigned short* __restrict__ Yb) {
    __shared__ alignas(16) char smem[32768];  // 2 x (K 8KB + V 8KB)

    int tid = threadIdx.x;
    int wid = tid >> 6, lane = tid & 63;
    int ql = lane & 31, hi = lane >> 5;
    int ql7 = ql & 7;

    // mapping: id -> (bh, g); second intra-XCD round flips g for CU balance
    int id = blockIdx.x;
    int x = id & 7;          // XCD
    int k = id >> 3;         // 0..63 within XCD
    int g = k & 7;
    if (k & 32) g = 7 - g;
    int bh = x * 8 + (k >> 3);
    size_t hb = (size_t)bh * (T_SEQ * HD);

    int qt = g * 8 + wid;             // this wave's 32-row q-tile
    int q0 = qt * 32;
    int ktMax = qt >> 1;              // last (diagonal) KV tile for this wave
    int ntB = 4 * g + 4;              // block's KV tile count (max over waves)

    // persistent Q B-frag (col=q=ql, elems d = dstep*16 + hi*8 + e)
    bf16x8 qf[4];
    const unsigned short* Qp = Qb + hb + (size_t)(q0 + ql) * HD + hi * 8;
#pragma unroll
    for (int d = 0; d < 4; ++d) qf[d] = *(const bf16x8*)(Qp + d * 16);

    f32x16 zz;
#pragma unroll
    for (int rr = 0; rr < 16; ++rr) zz[rr] = 0.f;
    f32x16 o0 = zz, o1 = zz;
    float mi = -__builtin_inff(), li = 0.f;

    // staging: 512 threads, 1 gld16 each for K and V; wave w covers rows [8w, 8w+8)
    int r8 = lane >> 3;
    int sslot8 = ((lane & 7) ^ r8) * 8;  // pre-swizzled source slot
    const unsigned short* Kg = Kb + hb + (size_t)(wid * 8 + r8) * HD + sslot8;
    const unsigned short* Vg = Vt + hb + (size_t)(wid * 8 + r8) * T_SEQ + sslot8;

    // prologue: stage kt=0 into buf 0
    gld16(Kg, smem + wid * 1024);
    gld16(Vg, smem + 8192 + wid * 1024);
    __syncthreads();

#define KF(K0, D) (*(const bf16x8*)&KB_[(((K0)*32 + ql) << 6) + ((((D)*2 + hi) ^ ql7) << 3)])
#define VF(DB, T) (*(const bf16x8*)&VB_[(((DB)*32 + ql) << 6) + ((((T)*2 + hi) ^ ql7) << 3)])

    for (int kt = 0; kt < ntB; ++kt) {
        int cur = kt & 1;
        bool pf = (kt + 1 < ntB);
        if (pf) {  // prefetch next tile into other buffer
            char* nb = smem + (cur ^ 1) * 16384;
            gld16(Kg + (size_t)(kt + 1) * 64 * HD, nb + wid * 1024);
            gld16(Vg + (kt + 1) * 64, nb + 8192 + wid * 1024);
        }
        // wait only the PREVIOUS iter's loads (cur's data); this iter's stay in flight
        if (pf) { asm volatile("s_waitcnt vmcnt(2)" ::: "memory"); }
        else    { asm volatile("s_waitcnt vmcnt(0)" ::: "memory"); }
        FENCE; __builtin_amdgcn_s_barrier(); FENCE;

        if (kt <= ktMax) {
            const unsigned short* KB_ = (const unsigned short*)(smem + cur * 16384);
            const unsigned short* VB_ = (const unsigned short*)(smem + cur * 16384 + 8192);
            int k0 = kt * 64;

            f32x16 s0_, s1_;
            __builtin_amdgcn_s_setprio(1);
            s0_ = mfma32(KF(0, 0), qf[0], zz);
            s0_ = mfma32(KF(0, 1), qf[1], s0_);
            s0_ = mfma32(KF(0, 2), qf[2], s0_);
            s0_ = mfma32(KF(0, 3), qf[3], s0_);
            s1_ = mfma32(KF(1, 0), qf[0], zz);
            s1_ = mfma32(KF(1, 1), qf[1], s1_);
            s1_ = mfma32(KF(1, 2), qf[2], s1_);
            s1_ = mfma32(KF(1, 3), qf[3], s1_);
            __builtin_amdgcn_s_setprio(0);

            if (kt == ktMax) {  // causal mask, diagonal tile only
                int qg_ = q0 + ql;
#pragma unroll
                for (int rr = 0; rr < 16; ++rr) {
                    int kof_ = k0 + 8 * (rr >> 2) + (rr & 3) + 4 * hi;
                    if (kof_ > qg_) s0_[rr] = -__builtin_inff();
                    if (kof_ + 32 > qg_) s1_[rr] = -__builtin_inff();
                }
            }

            // lane-local row max (exp2 domain; q pre-scaled by 0.125*log2e)
            float t_[8];
#pragma unroll
            for (int rr = 0; rr < 8; ++rr)
                t_[rr] = fmaxf(fmaxf(s0_[rr], s0_[rr + 8]), fmaxf(s1_[rr], s1_[rr + 8]));
#pragma unroll
            for (int rr = 0; rr < 4; ++rr) t_[rr] = fmaxf(t_[rr], t_[rr + 4]);
            float pm_ = fmaxf(fmaxf(t_[0], t_[1]), fmaxf(t_[2], t_[3]));
            pm_ = fmaxf(pm_, __shfl_xor(pm_, 32));

            float mn_ = mi;
            if (!__all((int)(pm_ <= mi + 8.f))) {  // defer-max
                mn_ = fmaxf(mi, pm_);
                float f_ = __builtin_amdgcn_exp2f(mi - mn_);
                mi = mn_;
                li *= f_;
                o0 *= f_;
                o1 *= f_;
            }
#pragma unroll
            for (int rr = 0; rr < 16; ++rr) {
                s0_[rr] = __builtin_amdgcn_exp2f(s0_[rr] - mn_);
                s1_[rr] = __builtin_amdgcn_exp2f(s1_[rr] - mn_);
            }
            float u_[8];
#pragma unroll
            for (int rr = 0; rr < 8; ++rr)
                u_[rr] = (s0_[rr] + s0_[rr + 8]) + (s1_[rr] + s1_[rr + 8]);
#pragma unroll
            for (int rr = 0; rr < 4; ++rr) u_[rr] += u_[rr + 4];
            float ps_ = (u_[0] + u_[1]) + (u_[2] + u_[3]);
            ps_ += __shfl_xor(ps_, 32);
            li += ps_;

            // P -> PV B-frag via cvt_pk + permlane32_swap, then O += V^T P^T
#pragma unroll
            for (int K0_ = 0; K0_ < 2; ++K0_) {
#pragma unroll
                for (int h2_ = 0; h2_ < 2; ++h2_) {
                    float e0_ = K0_ ? s1_[8 * h2_ + 0] : s0_[8 * h2_ + 0];
                    float e1_ = K0_ ? s1_[8 * h2_ + 1] : s0_[8 * h2_ + 1];
                    float e2_ = K0_ ? s1_[8 * h2_ + 2] : s0_[8 * h2_ + 2];
                    float e3_ = K0_ ? s1_[8 * h2_ + 3] : s0_[8 * h2_ + 3];
                    float e4_ = K0_ ? s1_[8 * h2_ + 4] : s0_[8 * h2_ + 4];
                    float e5_ = K0_ ? s1_[8 * h2_ + 5] : s0_[8 * h2_ + 5];
                    float e6_ = K0_ ? s1_[8 * h2_ + 6] : s0_[8 * h2_ + 6];
                    float e7_ = K0_ ? s1_[8 * h2_ + 7] : s0_[8 * h2_ + 7];
                    unsigned a_, b_, c_, d_;
                    asm("v_cvt_pk_bf16_f32 %0, %1, %2" : "=v"(a_) : "v"(e0_), "v"(e1_));
                    asm("v_cvt_pk_bf16_f32 %0, %1, %2" : "=v"(b_) : "v"(e2_), "v"(e3_));
                    asm("v_cvt_pk_bf16_f32 %0, %1, %2" : "=v"(c_) : "v"(e4_), "v"(e5_));
                    asm("v_cvt_pk_bf16_f32 %0, %1, %2" : "=v"(d_) : "v"(e6_), "v"(e7_));
                    asm("v_permlane32_swap_b32 %0, %1" : "+v"(a_), "+v"(c_));
                    asm("v_permlane32_swap_b32 %0, %1" : "+v"(b_), "+v"(d_));
                    union { unsigned u[4]; bf16x8 v; } pf_;
                    pf_.u[0] = a_; pf_.u[1] = b_; pf_.u[2] = c_; pf_.u[3] = d_;
                    __builtin_amdgcn_s_setprio(1);
                    o0 = mfma32(VF(0, K0_ * 2 + h2_), pf_.v, o0);
                    o1 = mfma32(VF(1, K0_ * 2 + h2_), pf_.v, o1);
                    __builtin_amdgcn_s_setprio(0);
                }
            }
        }
        asm volatile("s_waitcnt lgkmcnt(0)" ::: "memory");
        FENCE; __builtin_amdgcn_s_barrier(); FENCE;  // reads of cur done; no vm drain
    }
#undef KF
#undef VF

    // epilogue: O^T[d][q]: q = q0+ql, d = dblk*32 + 8a + i + 4hi
    int bb = bh >> 4, h = bh & 15;
    float iv = 1.0f / li;
#pragma unroll
    for (int dblk = 0; dblk < 2; ++dblk) {
#pragma unroll
        for (int a = 0; a < 4; ++a) {
            u16x4 wv;
#pragma unroll
            for (int i = 0; i < 4; ++i)
                wv[i] = f2b((dblk ? o1[4 * a + i] : o0[4 * a + i]) * iv);
            int dq = dblk * 32 + 8 * a + 4 * hi;
            *(u16x4*)&Yb[((size_t)(bb * T_SEQ + q0 + ql)) * CDIM + h * HD + dq] = wv;
        }
    }
}

// ---------------- launch ----------------
extern "C" void kernel_launch(void* const* d_in, const int* in_sizes, int n_in,
                              void* d_out, int out_size, void* d_ws, size_t ws_size,
                              hipStream_t stream) {
    const float* x      = (const float*)d_in[0];
    const float* w_attn = (const float*)d_in[1];
    const float* b_attn = (const float*)d_in[2];
    const float* w_proj = (const float*)d_in[3];
    const float* b_proj = (const float*)d_in[4];
    float* out = (float*)d_out;

    // workspace layout (bytes):
    //   0         xb  : x bf16 [8192][1024]         16,777,216  (reused as yb)
    //   16777216  wTa : w_attn^T bf16 [3072][1024]   6,291,456
    //   23068672  wTp : w_proj^T bf16 [1024][1024]   2,097,152
    //   25165824  qb  : [64][2048][64] bf16         16,777,216  (pre-scaled by QSCALE)
    //   41943040  kb  : [64][2048][64] bf16         16,777,216
    //   58720256  vTb : [64][64][2048] bf16         16,777,216  (V^T, written by GEMM1)
    char* ws = (char*)d_ws;
    unsigned short* xb  = (unsigned short*)(ws);
    unsigned short* wTa = (unsigned short*)(ws + 16777216);
    unsigned short* wTp = (unsigned short*)(ws + 23068672);
    unsigned short* qb  = (unsigned short*)(ws + 25165824);
    unsigned short* kb  = (unsigned short*)(ws + 41943040);
    unsigned short* vTb = (unsigned short*)(ws + 58720256);
    unsigned short* yb  = xb;  // alias: xb dead after GEMM1

    // fused prep: blocks [0,1024)=cast, [1024,4096)=w_attn^T, [4096,5120)=w_proj^T
    prep_kernel<<<dim3(5120), 256, 0, stream>>>(x, w_attn, w_proj, xb, wTa, wTp);

    // QKV GEMM: 1536 blocks, 24KB LDS -> 6 blocks/CU, K-rotated anti-convoy
    gemm_qkv_kernel<<<dim3(3072 / 128, 8192 / 128), 256, 0, stream>>>(
        xb, wTa, b_attn, qb, kb, vTb, 8192, 3072, 1024);

    // flash attention: 512 blocks x 8 waves (256 q-rows each), 2 blocks/CU
    attn32_kernel<<<dim3(512), 512, 0, stream>>>(qb, kb, vTb, yb);

    // proj GEMM -> fp32 out, K-rotated
    gemm_proj_kernel<<<dim3(1024 / 128, 8192 / 128), 256, 0, stream>>>(
        yb, wTp, b_proj, out, 8192, 1024, 1024);
}

// Round 14
// 169.259 us; speedup vs baseline: 1.0526x; 1.0526x over previous
//
#include <hip/hip_runtime.h>

// CausalSelfAttention: B=4, T=2048, C=1024, H=16, hd=64
// fused prep, QKV GEMM (128^2, A-single/B-dbuf, counted vmcnt, conflict-free swizzle),
// 8-wave flash attention (KVBLK=128, two 64-key substeps per barrier), proj GEMM

#define T_SEQ 2048
#define NB 4
#define NH 16
#define CDIM 1024
#define HD 64
#define BH (NB * NH)
#define QSCALE 0.1803368801111204f  // 0.125 * log2(e)

typedef float f32x4 __attribute__((ext_vector_type(4)));
typedef float f32x16 __attribute__((ext_vector_type(16)));
typedef __bf16 bf16x8 __attribute__((ext_vector_type(8)));
typedef unsigned short u16x8 __attribute__((ext_vector_type(8)));
typedef unsigned short u16x4 __attribute__((ext_vector_type(4)));

__device__ __forceinline__ unsigned short f2b(float f) {
    union { float f; unsigned u; } v; v.f = f;
    unsigned u = v.u;
    u += 0x7FFFu + ((u >> 16) & 1u);   // round-to-nearest-even
    return (unsigned short)(u >> 16);
}

__device__ __forceinline__ f32x4 fzero4() {
    f32x4 z; z[0] = 0.f; z[1] = 0.f; z[2] = 0.f; z[3] = 0.f; return z;
}

__device__ __forceinline__ f32x4 mfma16(bf16x8 a, bf16x8 b, f32x4 c) {
    return __builtin_amdgcn_mfma_f32_16x16x32_bf16(a, b, c, 0, 0, 0);
}

__device__ __forceinline__ f32x16 mfma32(bf16x8 a, bf16x8 b, f32x16 c) {
    return __builtin_amdgcn_mfma_f32_32x32x16_bf16(a, b, c, 0, 0, 0);
}

// async global->LDS, 16B/lane; LDS dest = wave-uniform base + lane*16 (HW rule)
__device__ __forceinline__ void gld16(const void* gp, void* lp) {
    __builtin_amdgcn_global_load_lds(
        (const __attribute__((address_space(1))) unsigned int*)gp,
        (__attribute__((address_space(3))) unsigned int*)lp, 16, 0, 0);
}

#define FENCE asm volatile("" ::: "memory")

// ---------------- fused prep: cast x, transpose w_attn, transpose w_proj ----------------
__device__ __forceinline__ void transpose_tile(
        const float* __restrict__ in, unsigned short* __restrict__ out,
        int R, int C, int bx, int by) {
    __shared__ unsigned short tile[32][33];
    int tx = threadIdx.x & 31, ty = threadIdx.x >> 5;
    int c0 = bx * 32, r0 = by * 32;
#pragma unroll
    for (int rr = ty; rr < 32; rr += 8)
        tile[rr][tx] = f2b(in[(size_t)(r0 + rr) * C + c0 + tx]);
    __syncthreads();
#pragma unroll
    for (int rr = ty; rr < 32; rr += 8)
        out[(size_t)(c0 + rr) * R + r0 + tx] = tile[tx][rr];
}

__global__ __launch_bounds__(256) void prep_kernel(
        const float* __restrict__ x, const float* __restrict__ wa,
        const float* __restrict__ wp, unsigned short* __restrict__ xb,
        unsigned short* __restrict__ wTa, unsigned short* __restrict__ wTp) {
    int b = blockIdx.x;
    if (b < 1024) {
        int n8 = (NB * T_SEQ * CDIM) / 8;
        for (int i = b * 256 + threadIdx.x; i < n8; i += 1024 * 256) {
            const float4* p = reinterpret_cast<const float4*>(x) + (size_t)i * 2;
            float4 a = p[0], c = p[1];
            u16x8 o;
            o[0] = f2b(a.x); o[1] = f2b(a.y); o[2] = f2b(a.z); o[3] = f2b(a.w);
            o[4] = f2b(c.x); o[5] = f2b(c.y); o[6] = f2b(c.z); o[7] = f2b(c.w);
            *(reinterpret_cast<u16x8*>(xb) + i) = o;
        }
    } else if (b < 1024 + 3072) {
        int t = b - 1024;   // w_attn [1024][3072]: 96 x 32 tiles
        transpose_tile(wa, wTa, 1024, 3072, t % 96, t / 96);
    } else {
        int t = b - 4096;   // w_proj [1024][1024]: 32 x 32 tiles
        transpose_tile(wp, wTp, 1024, 1024, t % 32, t / 32);
    }
}

// ---------------- QKV GEMM: 128^2, A-single + B-dbuf (24KB -> 6 blocks/CU) ----------------
__global__ __launch_bounds__(256) void gemm_qkv_kernel(
        const unsigned short* __restrict__ A, const unsigned short* __restrict__ Bt,
        const float* __restrict__ bias,
        unsigned short* __restrict__ q_out, unsigned short* __restrict__ k_out,
        unsigned short* __restrict__ v_out, int M, int N, int K) {
    __shared__ alignas(16) unsigned short As[128 * 32];     // 8KB single
    __shared__ alignas(16) unsigned short Bs[2][128 * 32];  // 16KB dbuf

    int tid = threadIdx.x;
    int wid = tid >> 6, lane = tid & 63;
    int g = lane >> 4, lc = lane & 15;
    int wr = (wid >> 1) * 64, wc = (wid & 1) * 64;
    int m0 = blockIdx.y * 128, n0 = blockIdx.x * 128;

    f32x4 acc[4][4];
#pragma unroll
    for (int m = 0; m < 4; ++m)
#pragma unroll
        for (int n = 0; n < 4; ++n) acc[m][n] = fzero4();

    int srow = tid >> 2;
    int scol = ((tid & 3) ^ ((srow >> 1) & 3)) * 8;  // inverse-swizzled source col
    const unsigned short* Ap = A + (size_t)(m0 + srow) * K + scol;
    const unsigned short* Bp = Bt + (size_t)(n0 + srow) * K + scol;
    int ldst = (wid * 16) * 32;
    int ldst2 = (64 + wid * 16) * 32;

#define STAGE_A(KOFF) {                                    \
        gld16(Ap + (KOFF), &As[ldst]);                     \
        gld16(Ap + (size_t)64 * K + (KOFF), &As[ldst2]); }
#define STAGE_B(BUF, KOFF) {                                       \
        gld16(Bp + (KOFF), &Bs[BUF][ldst]);                        \
        gld16(Bp + (size_t)64 * K + (KOFF), &Bs[BUF][ldst2]); }

    STAGE_B(0, 0)    // B(0)
    STAGE_A(0)       // A(0)
    STAGE_B(1, 32)   // B(1)

    int swz8 = (g ^ ((lc >> 1) & 3)) * 8;  // read slot swizzle ((row>>1)&3 == (lc>>1)&3)

    int nk = K >> 5;
    for (int it = 0; it < nk; ++it) {
        if (it + 1 < nk) { asm volatile("s_waitcnt vmcnt(2)" ::: "memory"); }
        else             { asm volatile("s_waitcnt vmcnt(0)" ::: "memory"); }
        FENCE; __builtin_amdgcn_s_barrier(); FENCE;  // A(it), B(it) visible

        bf16x8 af[4], bfr[4];
        const unsigned short* Bb = Bs[it & 1];
#pragma unroll
        for (int m = 0; m < 4; ++m)
            af[m] = *(const bf16x8*)&As[(wr + m * 16 + lc) * 32 + swz8];
#pragma unroll
        for (int n = 0; n < 4; ++n)
            bfr[n] = *(const bf16x8*)&Bb[(wc + n * 16 + lc) * 32 + swz8];

        __builtin_amdgcn_s_setprio(1);
#pragma unroll
        for (int m = 0; m < 4; ++m)
#pragma unroll
            for (int n = 0; n < 4; ++n)
                acc[m][n] = mfma16(af[m], bfr[n], acc[m][n]);
        __builtin_amdgcn_s_setprio(0);

        asm volatile("s_waitcnt lgkmcnt(0)" ::: "memory");
        FENCE; __builtin_amdgcn_s_barrier(); FENCE;  // all reads consumed
        if (it + 1 < nk) STAGE_A((it + 1) << 5)
        if (it + 2 < nk) STAGE_B(it & 1, (it + 2) << 5)
    }
#undef STAGE_A
#undef STAGE_B

    // epilogue: scatter q (scaled), k row-major; v transposed per head
#pragma unroll
    for (int m = 0; m < 4; ++m) {
        int rowb = m0 + wr + m * 16 + g * 4;
#pragma unroll
        for (int n = 0; n < 4; ++n) {
            int col = n0 + wc + n * 16 + lc;
            float bv = bias[col];
            int which = col >> 10;
            int c = col & 1023;
            int h = c >> 6, d = c & 63;
            int bh_ = (rowb >> 11) * NH + h;
            int tl = rowb & 2047;
            if (which == 2) {
                u16x4 vq;
#pragma unroll
                for (int i = 0; i < 4; ++i) vq[i] = f2b(acc[m][n][i] + bv);
                *(u16x4*)&v_out[(size_t)bh_ * (HD * T_SEQ) + (size_t)d * T_SEQ + tl] = vq;
            } else {
                unsigned short* dst = which ? k_out : q_out;
                float sc = which ? 1.0f : QSCALE;
#pragma unroll
                for (int i = 0; i < 4; ++i)
                    dst[((size_t)bh_ * T_SEQ + tl + i) * HD + d] =
                        f2b((acc[m][n][i] + bv) * sc);
            }
        }
    }
}

// ---------------- proj GEMM: 128^2 2-phase dbuf + counted vmcnt ----------
__global__ __launch_bounds__(256) void gemm_proj_kernel(
        const unsigned short* __restrict__ A, const unsigned short* __restrict__ Bt,
        const float* __restrict__ bias, float* __restrict__ outF, int M, int N, int K) {
    __shared__ alignas(16) unsigned short As[2][128 * 32];
    __shared__ alignas(16) unsigned short Bs[2][128 * 32];

    int tid = threadIdx.x;
    int wid = tid >> 6, lane = tid & 63;
    int g = lane >> 4, lc = lane & 15;
    int wr = (wid >> 1) * 64, wc = (wid & 1) * 64;
    int m0 = blockIdx.y * 128, n0 = blockIdx.x * 128;

    f32x4 acc[4][4];
#pragma unroll
    for (int m = 0; m < 4; ++m)
#pragma unroll
        for (int n = 0; n < 4; ++n) acc[m][n] = fzero4();

    int srow = tid >> 2;
    int scol = ((tid & 3) ^ ((srow >> 1) & 3)) * 8;
    const unsigned short* Ap = A + (size_t)(m0 + srow) * K + scol;
    const unsigned short* Bp = Bt + (size_t)(n0 + srow) * K + scol;
    int ldst = (wid * 16) * 32;
    int ldst2 = (64 + wid * 16) * 32;

#define GSTAGE(BUF, KOFF)                                      \
    gld16(Ap + (KOFF), &As[BUF][ldst]);                        \
    gld16(Ap + (size_t)64 * K + (KOFF), &As[BUF][ldst2]);      \
    gld16(Bp + (KOFF), &Bs[BUF][ldst]);                        \
    gld16(Bp + (size_t)64 * K + (KOFF), &Bs[BUF][ldst2]);

    GSTAGE(0, 0)
    GSTAGE(1, 32)

    int swz8 = (g ^ ((lc >> 1) & 3)) * 8;

    int nk = K >> 5;
    for (int it = 0; it < nk; ++it) {
        int cur = it & 1;
        if (it + 1 < nk) { asm volatile("s_waitcnt vmcnt(4)" ::: "memory"); }
        else             { asm volatile("s_waitcnt vmcnt(0)" ::: "memory"); }
        FENCE; __builtin_amdgcn_s_barrier(); FENCE;

        bf16x8 af[4], bfr[4];
#pragma unroll
        for (int m = 0; m < 4; ++m)
            af[m] = *(const bf16x8*)&As[cur][(wr + m * 16 + lc) * 32 + swz8];
#pragma unroll
        for (int n = 0; n < 4; ++n)
            bfr[n] = *(const bf16x8*)&Bs[cur][(wc + n * 16 + lc) * 32 + swz8];

        __builtin_amdgcn_s_setprio(1);
#pragma unroll
        for (int m = 0; m < 4; ++m)
#pragma unroll
            for (int n = 0; n < 4; ++n)
                acc[m][n] = mfma16(af[m], bfr[n], acc[m][n]);
        __builtin_amdgcn_s_setprio(0);

        FENCE; __builtin_amdgcn_s_barrier(); FENCE;
        if (it + 2 < nk) { GSTAGE(cur, (it + 2) << 5) }
    }
#undef GSTAGE

#pragma unroll
    for (int m = 0; m < 4; ++m) {
        int rowb = m0 + wr + m * 16 + g * 4;
#pragma unroll
        for (int n = 0; n < 4; ++n) {
            int col = n0 + wc + n * 16 + lc;
            float bv = bias[col];
#pragma unroll
            for (int i = 0; i < 4; ++i)
                outF[(size_t)(rowb + i) * N + col] = acc[m][n][i] + bv;
        }
    }
}

// ---------------- flash attention: 8 waves/block, KVBLK=128 ----------------
// 512 blocks x 512 thr. Block = (head, g): q-tiles g*8 + wid (32 rows each).
// KV tile = 128 keys (K 16KB + V 16KB, dbuf 64KB -> 2 blocks/CU). Each barrier
// round covers TWO 64-key substeps (same regs) -> half the barrier/vmcnt iters.
__global__ __launch_bounds__(512, 4) void attn32_kernel(
        const unsigned short* __restrict__ Qb, const unsigned short* __restrict__ Kb,
        const unsigned short* __restrict__ Vt, unsigned short* __restrict__ Yb) {
    __shared__ alignas(16) char smem[65536];  // 2 x (K 16KB + V 16KB)

    int tid = threadIdx.x;
    int wid = tid >> 6, lane = tid & 63;
    int ql = lane & 31, hi = lane >> 5;
    int ql7 = ql & 7;

    // mapping: id -> (bh, g); second intra-XCD round flips g for CU balance
    int id = blockIdx.x;
    int x = id & 7;          // XCD
    int k = id >> 3;         // 0..63 within XCD
    int g = k & 7;
    if (k & 32) g = 7 - g;
    int bh = x * 8 + (k >> 3);
    size_t hb = (size_t)bh * (T_SEQ * HD);

    int qt = g * 8 + wid;             // this wave's 32-row q-tile
    int q0 = qt * 32;
    int ktMax = qt >> 2;              // last (diagonal) 128-key tile for this wave
    int ntB = 2 * g + 2;              // block's 128-key tile count (max over waves)
    int nsubDiag = ((qt & 3) >= 2) ? 2 : 1;  // substeps needed in the diagonal tile

    // persistent Q B-frag (col=q=ql, elems d = dstep*16 + hi*8 + e)
    bf16x8 qf[4];
    const unsigned short* Qp = Qb + hb + (size_t)(q0 + ql) * HD + hi * 8;
#pragma unroll
    for (int d = 0; d < 4; ++d) qf[d] = *(const bf16x8*)(Qp + d * 16);

    f32x16 zz;
#pragma unroll
    for (int rr = 0; rr < 16; ++rr) zz[rr] = 0.f;
    f32x16 o0 = zz, o1 = zz;
    float mi = -__builtin_inff(), li = 0.f;

    // K staging: wave w covers key-rows [8w,8w+8) and [64+8w,64+8w+8); 64-short rows
    int kr = wid * 8 + (lane >> 3);
    int kslot8 = ((lane & 7) ^ (kr & 7)) * 8;          // pre-swizzled source slot
    const unsigned short* Kg = Kb + hb + (size_t)kr * HD + kslot8;
    // V staging: wave w covers d-rows [4w,4w+4) and [32+4w,32+4w+4); 128-short rows
    int vr = wid * 4 + (lane >> 4);
    int vslot8 = ((lane & 15) ^ (vr & 7)) * 8;         // 16 slots/row, XOR low 3 bits
    const unsigned short* Vg = Vt + hb + (size_t)vr * T_SEQ + vslot8;

    // prologue: stage kt=0 into buf 0 (K: 2 gld16, V: 2 gld16)
    gld16(Kg, smem + wid * 1024);
    gld16(Kg + (size_t)64 * HD, smem + 8192 + wid * 1024);
    gld16(Vg, smem + 16384 + wid * 1024);
    gld16(Vg + (size_t)32 * T_SEQ, smem + 16384 + 8192 + wid * 1024);
    __syncthreads();

// K LDS: [128 keys][64 d] shorts, row stride 64; slot swizzle ^ (row&7)
#define KF(K0, D) (*(const bf16x8*)&KB_[(((K0)*32 + ql) << 6) + ((((D)*2 + hi) ^ ql7) << 3)])
// V LDS: [64 d][128 keys] shorts, row stride 128; 16 slots, swizzle ^ (row&7) (low 3 bits)
#define VF(DB, SL) (*(const bf16x8*)&VB_[(((DB)*32 + ql) << 7) + (((SL) ^ ql7) << 3)])

    for (int kt = 0; kt < ntB; ++kt) {
        int cur = kt & 1;
        bool pf = (kt + 1 < ntB);
        if (pf) {  // prefetch next 128-key tile into other buffer
            char* nb = smem + (cur ^ 1) * 32768;
            int k0n = (kt + 1) << 7;
            gld16(Kg + (size_t)k0n * HD, nb + wid * 1024);
            gld16(Kg + (size_t)(k0n + 64) * HD, nb + 8192 + wid * 1024);
            gld16(Vg + k0n, nb + 16384 + wid * 1024);
            gld16(Vg + (size_t)32 * T_SEQ + k0n, nb + 16384 + 8192 + wid * 1024);
        }
        // wait only the PREVIOUS iter's 4 loads; this iter's 4 stay in flight
        if (pf) { asm volatile("s_waitcnt vmcnt(4)" ::: "memory"); }
        else    { asm volatile("s_waitcnt vmcnt(0)" ::: "memory"); }
        FENCE; __builtin_amdgcn_s_barrier(); FENCE;

        if (kt <= ktMax) {
            const unsigned short* KB_ = (const unsigned short*)(smem + cur * 32768);
            const unsigned short* VB_ = (const unsigned short*)(smem + cur * 32768 + 16384);
            int k0 = kt << 7;
            bool diagT = (kt == ktMax);
            int nsub = diagT ? nsubDiag : 2;

            for (int sub = 0; sub < nsub; ++sub) {
                int kb_ = k0 + (sub << 6);
                int K0b = sub * 2;

                f32x16 s0_, s1_;
                __builtin_amdgcn_s_setprio(1);
                s0_ = mfma32(KF(K0b, 0), qf[0], zz);
                s0_ = mfma32(KF(K0b, 1), qf[1], s0_);
                s0_ = mfma32(KF(K0b, 2), qf[2], s0_);
                s0_ = mfma32(KF(K0b, 3), qf[3], s0_);
                s1_ = mfma32(KF(K0b + 1, 0), qf[0], zz);
                s1_ = mfma32(KF(K0b + 1, 1), qf[1], s1_);
                s1_ = mfma32(KF(K0b + 1, 2), qf[2], s1_);
                s1_ = mfma32(KF(K0b + 1, 3), qf[3], s1_);
                __builtin_amdgcn_s_setprio(0);

                if (diagT && sub == nsub - 1) {  // causal mask, diagonal substep only
                    int qg_ = q0 + ql;
#pragma unroll
                    for (int rr = 0; rr < 16; ++rr) {
                        int kof_ = kb_ + 8 * (rr >> 2) + (rr & 3) + 4 * hi;
                        if (kof_ > qg_) s0_[rr] = -__builtin_inff();
                        if (kof_ + 32 > qg_) s1_[rr] = -__builtin_inff();
                    }
                }

                // lane-local row max (exp2 domain; q pre-scaled by 0.125*log2e)
                float t_[8];
#pragma unroll
                for (int rr = 0; rr < 8; ++rr)
                    t_[rr] = fmaxf(fmaxf(s0_[rr], s0_[rr + 8]), fmaxf(s1_[rr], s1_[rr + 8]));
#pragma unroll
                for (int rr = 0; rr < 4; ++rr) t_[rr] = fmaxf(t_[rr], t_[rr + 4]);
                float pm_ = fmaxf(fmaxf(t_[0], t_[1]), fmaxf(t_[2], t_[3]));
                pm_ = fmaxf(pm_, __shfl_xor(pm_, 32));

                float mn_ = mi;
                if (!__all((int)(pm_ <= mi + 8.f))) {  // defer-max
                    mn_ = fmaxf(mi, pm_);
                    float f_ = __builtin_amdgcn_exp2f(mi - mn_);
                    mi = mn_;
                    li *= f_;
                    o0 *= f_;
                    o1 *= f_;
                }
#pragma unroll
                for (int rr = 0; rr < 16; ++rr) {
                    s0_[rr] = __builtin_amdgcn_exp2f(s0_[rr] - mn_);
                    s1_[rr] = __builtin_amdgcn_exp2f(s1_[rr] - mn_);
                }
                float u_[8];
#pragma unroll
                for (int rr = 0; rr < 8; ++rr)
                    u_[rr] = (s0_[rr] + s0_[rr + 8]) + (s1_[rr] + s1_[rr + 8]);
#pragma unroll
                for (int rr = 0; rr < 4; ++rr) u_[rr] += u_[rr + 4];
                float ps_ = (u_[0] + u_[1]) + (u_[2] + u_[3]);
                ps_ += __shfl_xor(ps_, 32);
                li += ps_;

                // P -> PV B-frag via cvt_pk + permlane32_swap, then O += V^T P^T
#pragma unroll
                for (int K0_ = 0; K0_ < 2; ++K0_) {
#pragma unroll
                    for (int h2_ = 0; h2_ < 2; ++h2_) {
                        float e0_ = K0_ ? s1_[8 * h2_ + 0] : s0_[8 * h2_ + 0];
                        float e1_ = K0_ ? s1_[8 * h2_ + 1] : s0_[8 * h2_ + 1];
                        float e2_ = K0_ ? s1_[8 * h2_ + 2] : s0_[8 * h2_ + 2];
                        float e3_ = K0_ ? s1_[8 * h2_ + 3] : s0_[8 * h2_ + 3];
                        float e4_ = K0_ ? s1_[8 * h2_ + 4] : s0_[8 * h2_ + 4];
                        float e5_ = K0_ ? s1_[8 * h2_ + 5] : s0_[8 * h2_ + 5];
                        float e6_ = K0_ ? s1_[8 * h2_ + 6] : s0_[8 * h2_ + 6];
                        float e7_ = K0_ ? s1_[8 * h2_ + 7] : s0_[8 * h2_ + 7];
                        unsigned a_, b_, c_, d_;
                        asm("v_cvt_pk_bf16_f32 %0, %1, %2" : "=v"(a_) : "v"(e0_), "v"(e1_));
                        asm("v_cvt_pk_bf16_f32 %0, %1, %2" : "=v"(b_) : "v"(e2_), "v"(e3_));
                        asm("v_cvt_pk_bf16_f32 %0, %1, %2" : "=v"(c_) : "v"(e4_), "v"(e5_));
                        asm("v_cvt_pk_bf16_f32 %0, %1, %2" : "=v"(d_) : "v"(e6_), "v"(e7_));
                        asm("v_permlane32_swap_b32 %0, %1" : "+v"(a_), "+v"(c_));
                        asm("v_permlane32_swap_b32 %0, %1" : "+v"(b_), "+v"(d_));
                        union { unsigned u[4]; bf16x8 v; } pf_;
                        pf_.u[0] = a_; pf_.u[1] = b_; pf_.u[2] = c_; pf_.u[3] = d_;
                        int sl_ = (sub << 3) + (K0_ * 2 + h2_) * 2 + hi;
                        __builtin_amdgcn_s_setprio(1);
                        o0 = mfma32(VF(0, sl_), pf_.v, o0);
                        o1 = mfma32(VF(1, sl_), pf_.v, o1);
                        __builtin_amdgcn_s_setprio(0);
                    }
                }
            }
        }
        asm volatile("s_waitcnt lgkmcnt(0)" ::: "memory");
        FENCE; __builtin_amdgcn_s_barrier(); FENCE;  // reads of cur done; no vm drain
    }
#undef KF
#undef VF

    // epilogue: O^T[d][q]: q = q0+ql, d = dblk*32 + 8a + i + 4hi
    int bb = bh >> 4, h = bh & 15;
    float iv = 1.0f / li;
#pragma unroll
    for (int dblk = 0; dblk < 2; ++dblk) {
#pragma unroll
        for (int a = 0; a < 4; ++a) {
            u16x4 wv;
#pragma unroll
            for (int i = 0; i < 4; ++i)
                wv[i] = f2b((dblk ? o1[4 * a + i] : o0[4 * a + i]) * iv);
            int dq = dblk * 32 + 8 * a + 4 * hi;
            *(u16x4*)&Yb[((size_t)(bb * T_SEQ + q0 + ql)) * CDIM + h * HD + dq] = wv;
        }
    }
}

// ---------------- launch ----------------
extern "C" void kernel_launch(void* const* d_in, const int* in_sizes, int n_in,
                              void* d_out, int out_size, void* d_ws, size_t ws_size,
                              hipStream_t stream) {
    const float* x      = (const float*)d_in[0];
    const float* w_attn = (const float*)d_in[1];
    const float* b_attn = (const float*)d_in[2];
    const float* w_proj = (const float*)d_in[3];
    const float* b_proj = (const float*)d_in[4];
    float* out = (float*)d_out;

    // workspace layout (bytes):
    //   0         xb  : x bf16 [8192][1024]         16,777,216  (reused as yb)
    //   16777216  wTa : w_attn^T bf16 [3072][1024]   6,291,456
    //   23068672  wTp : w_proj^T bf16 [1024][1024]   2,097,152
    //   25165824  qb  : [64][2048][64] bf16         16,777,216  (pre-scaled by QSCALE)
    //   41943040  kb  : [64][2048][64] bf16         16,777,216
    //   58720256  vTb : [64][64][2048] bf16         16,777,216  (V^T, written by GEMM1)
    char* ws = (char*)d_ws;
    unsigned short* xb  = (unsigned short*)(ws);
    unsigned short* wTa = (unsigned short*)(ws + 16777216);
    unsigned short* wTp = (unsigned short*)(ws + 23068672);
    unsigned short* qb  = (unsigned short*)(ws + 25165824);
    unsigned short* kb  = (unsigned short*)(ws + 41943040);
    unsigned short* vTb = (unsigned short*)(ws + 58720256);
    unsigned short* yb  = xb;  // alias: xb dead after GEMM1

    // fused prep: blocks [0,1024)=cast, [1024,4096)=w_attn^T, [4096,5120)=w_proj^T
    prep_kernel<<<dim3(5120), 256, 0, stream>>>(x, w_attn, w_proj, xb, wTa, wTp);

    // QKV GEMM: 1536 blocks, 24KB LDS -> 6 blocks/CU
    gemm_qkv_kernel<<<dim3(3072 / 128, 8192 / 128), 256, 0, stream>>>(
        xb, wTa, b_attn, qb, kb, vTb, 8192, 3072, 1024);

    // flash attention: 512 blocks x 8 waves, KVBLK=128, 2 blocks/CU
    attn32_kernel<<<dim3(512), 512, 0, stream>>>(qb, kb, vTb, yb);

    // proj GEMM -> fp32 out
    gemm_proj_kernel<<<dim3(1024 / 128, 8192 / 128), 256, 0, stream>>>(
        yb, wTp, b_proj, out, 8192, 1024, 1024);
}